// Round 1
// baseline (218.444 us; speedup 1.0000x reference)
//
#include <hip/hip_runtime.h>

// DeepFM fused kernel for MI355X (gfx950).
// Strategy:
//  - prep kernel: repack Wm/Wu (augmented with FM sum-cols + additive col),
//    W1, W2 into bf16 MFMA A-fragment order in d_ws; compute bias sums.
//  - main kernel: 256 blocks x 512 threads, 64 batch rows per block.
//    All GEMMs computed transposed (weights = M operand) so outputs emerge
//    as k-contiguous strips that pack straight into the next layer's
//    B-fragment layout in LDS. FM sum + additive come from augmented
//    weight columns; fp32 accumulate throughout.

#define RB  64     // rows per block
#define NTH 512    // 8 waves

typedef __bf16 bf16x8 __attribute__((ext_vector_type(8)));
typedef float  f32x4  __attribute__((ext_vector_type(4)));

// workspace layout (bytes)
#define WS_WMF  0          // movie tower A-frags: [16 ks][18 ft][64][16B] = 294912
#define WS_WUF  294912     // user tower A-frags
#define WS_W1F  589824     // W1 A-frags: [16 ks][16 ft][64][16B] = 262144
#define WS_W2F  851968     // W2 A-frags: [8 ks][8 ft][64][16B] = 65536
#define WS_BIAS 917504     // fp32: bms[16], bus[16], badd(=bm[256]+bu[256]+b3)

#define LDS_BYTES 143616

__device__ __forceinline__ unsigned short f2bf(float f) {
  unsigned u = __builtin_bit_cast(unsigned, f);
  u += 0x7FFFu + ((u >> 16) & 1u);           // RNE
  return (unsigned short)(u >> 16);
}

__device__ __forceinline__ f32x4 mfma_bf16(bf16x8 a, bf16x8 b, f32x4 c) {
  return __builtin_amdgcn_mfma_f32_16x16x32_bf16(a, b, c, 0, 0, 0);
}

// ---------------------------------------------------------------------------
// Prep: build fragment-ordered bf16 weights + bias aux in ws.
// A-fragment element (ks, ft, lane l, e):  f = ft*16 + (l&15),
//   k = ks*32 + (l>>4)*8 + e,  value = Wt[f][k] (transposed-weight view).
// Tower augmented features: f<256 raw col f; 256..271 = sum_i W[:, i*16+(f-256)]
// (FM column sums); 272 = W[:,256] (additive); 273..287 = 0.
// ---------------------------------------------------------------------------
extern "C" __global__ __launch_bounds__(64) void deepfm_prep(
    const float* __restrict__ Wm, const float* __restrict__ bm,
    const float* __restrict__ Wu, const float* __restrict__ bu,
    const float* __restrict__ W1, const float* __restrict__ W2,
    const float* __restrict__ b3, char* __restrict__ ws) {
  const int bid = blockIdx.x;
  const int l = threadIdx.x;
  const int fi = l & 15, q = l >> 4;
  unsigned short h[8];
  if (bid < 576) {                       // towers: 2 x 16 ks x 18 ft
    const int t = bid / 288, rem = bid % 288;
    const int ks = rem / 18, ft = rem % 18;
    const float* W = t ? Wu : Wm;
    char* outp = ws + (t ? WS_WUF : WS_WMF);
    const int f = ft * 16 + fi;
#pragma unroll
    for (int e = 0; e < 8; ++e) {
      const int k = ks * 32 + q * 8 + e;
      float val;
      if (f < 256) val = W[k * 257 + f];
      else if (f < 272) {
        float s = 0.f;
        for (int i = 0; i < 16; ++i) s += W[k * 257 + i * 16 + (f - 256)];
        val = s;
      } else if (f == 272) val = W[k * 257 + 256];
      else val = 0.f;
      h[e] = f2bf(val);
    }
    uint4 o;
    o.x = h[0] | ((unsigned)h[1] << 16); o.y = h[2] | ((unsigned)h[3] << 16);
    o.z = h[4] | ((unsigned)h[5] << 16); o.w = h[6] | ((unsigned)h[7] << 16);
    *(uint4*)(outp + (((ks * 18 + ft) * 64 + l) << 4)) = o;
  } else if (bid < 832) {                // W1: 16 ks x 16 ft
    const int bb = bid - 576;
    const int ks = bb / 16, ft = bb % 16;
    const int f = ft * 16 + fi;
#pragma unroll
    for (int e = 0; e < 8; ++e) h[e] = f2bf(W1[(ks * 32 + q * 8 + e) * 256 + f]);
    uint4 o;
    o.x = h[0] | ((unsigned)h[1] << 16); o.y = h[2] | ((unsigned)h[3] << 16);
    o.z = h[4] | ((unsigned)h[5] << 16); o.w = h[6] | ((unsigned)h[7] << 16);
    *(uint4*)(ws + WS_W1F + (((ks * 16 + ft) * 64 + l) << 4)) = o;
  } else if (bid < 896) {                // W2: 8 ks x 8 ft
    const int bb = bid - 832;
    const int ks = bb / 8, ft = bb % 8;
    const int f = ft * 16 + fi;
#pragma unroll
    for (int e = 0; e < 8; ++e) h[e] = f2bf(W2[(ks * 32 + q * 8 + e) * 128 + f]);
    uint4 o;
    o.x = h[0] | ((unsigned)h[1] << 16); o.y = h[2] | ((unsigned)h[3] << 16);
    o.z = h[4] | ((unsigned)h[5] << 16); o.w = h[6] | ((unsigned)h[7] << 16);
    *(uint4*)(ws + WS_W2F + (((ks * 8 + ft) * 64 + l) << 4)) = o;
  } else {                               // bias aux
    float* aux = (float*)(ws + WS_BIAS);
    if (l < 16) {
      float s = 0.f;
      for (int i = 0; i < 16; ++i) s += bm[i * 16 + l];
      aux[l] = s;
    } else if (l < 32) {
      const int k = l - 16;
      float s = 0.f;
      for (int i = 0; i < 16; ++i) s += bu[i * 16 + k];
      aux[l] = s;
    } else if (l == 32) {
      aux[32] = bm[256] + bu[256] + b3[0];
    }
  }
}

// ---------------------------------------------------------------------------
// Main fused kernel.
// LDS: wbuf 36864 | infrag 8192 | densefrag 65536 | h1frag 32768 | outpart 256
// ---------------------------------------------------------------------------
extern "C" __global__ __launch_bounds__(NTH, 2) void deepfm_main(
    const float* __restrict__ movie, const float* __restrict__ user,
    const float* __restrict__ bm, const float* __restrict__ bu,
    const float* __restrict__ b1, const float* __restrict__ b2,
    const float* __restrict__ W3, const char* __restrict__ ws,
    float* __restrict__ out) {
  extern __shared__ __align__(16) char lds[];
  char* const wbuf      = lds;             // weight-frag staging (all phases)
  char* const infrag    = lds + 36864;     // input B-frags per 64k chunk
  char* const densefrag = lds + 45056;     // all_dense B-frags [16 kg][4 rt][64][16]
  char* const h1frag    = lds + 110592;    // h1 B-frags [8 kg][4 rt][64][16]
  float* const outpart  = (float*)(lds + 143360);

  const int tid = threadIdx.x;
  const int w   = tid >> 6;        // wave 0..7
  const int l   = tid & 63;
  const int cn  = l & 15;          // batch-row within 16 (MFMA n / C col)
  const int q   = l >> 4;
  const int row0 = blockIdx.x * RB;
  const int auxrt = w & 3;         // rt this wave owns for aux (FM) tiles

  if (tid < 64) outpart[tid] = 0.f;

  const f32x4 zz = {0.f, 0.f, 0.f, 0.f};
  f32x4 accA[2][4];                // 2 ft-slots x 4 rt (reused across phases)
  f32x4 accM = zz, accU = zz;      // aux: w<4: ms/us(rt=w); w>=4: additive(rt=w-4)

  const float* auxb = (const float*)(ws + WS_BIAS);

  // ---------------- Phase 1: towers (feats = 256 dense + 16 sum + 1 additive)
  for (int t = 0; t < 2; ++t) {
    const float* inp = t ? user : movie;
    const char* WF = ws + (t ? WS_WUF : WS_WMF);
#pragma unroll
    for (int s = 0; s < 2; ++s)
#pragma unroll
      for (int rt = 0; rt < 4; ++rt) accA[s][rt] = zz;

    for (int c = 0; c < 8; ++c) {          // 8 chunks of 64 k
      __syncthreads();
      {  // stage weight frags: [2 ks][18 ft][64][16B] = 36864B flat
        const uint4* g = (const uint4*)(WF + c * 36864);
        uint4* d = (uint4*)wbuf;
        for (int j = tid; j < 2304; j += NTH) d[j] = g[j];
      }
      // stage input rows as B-frags (fp32 -> bf16)
      for (int j = tid; j < 1024; j += NTH) {
        const int r = j >> 4, k4 = j & 15;
        const float4 v = *(const float4*)(inp + (size_t)(row0 + r) * 512 + c * 64 + k4 * 4);
        const int kl = k4 * 4;
        const int ks = kl >> 5, qq = (kl >> 3) & 3;
        uint2 p;
        p.x = f2bf(v.x) | ((unsigned)f2bf(v.y) << 16);
        p.y = f2bf(v.z) | ((unsigned)f2bf(v.w) << 16);
        *(uint2*)(infrag + (((ks * 4 + (r >> 4)) * 64 + qq * 16 + (r & 15)) << 4) +
                  ((kl & 4) ? 8 : 0)) = p;
      }
      __syncthreads();
#pragma unroll
      for (int ks = 0; ks < 2; ++ks) {
        bf16x8 bfr[4];
#pragma unroll
        for (int rt = 0; rt < 4; ++rt)
          bfr[rt] = *(const bf16x8*)(infrag + (((ks * 4 + rt) * 64 + l) << 4));
        const bf16x8 a0 = *(const bf16x8*)(wbuf + (((ks * 18 + w) * 64 + l) << 4));
        const bf16x8 a1 = *(const bf16x8*)(wbuf + (((ks * 18 + w + 8) * 64 + l) << 4));
        const bf16x8 ax = *(const bf16x8*)(wbuf + (((ks * 18 + (w < 4 ? 16 : 17)) * 64 + l) << 4));
#pragma unroll
        for (int rt = 0; rt < 4; ++rt) accA[0][rt] = mfma_bf16(a0, bfr[rt], accA[0][rt]);
#pragma unroll
        for (int rt = 0; rt < 4; ++rt) accA[1][rt] = mfma_bf16(a1, bfr[rt], accA[1][rt]);
        if (w < 4) {
          if (t == 0) accM = mfma_bf16(ax, bfr[auxrt], accM);
          else        accU = mfma_bf16(ax, bfr[auxrt], accU);
        } else {
          accM = mfma_bf16(ax, bfr[auxrt], accM);   // additive: both towers
        }
      }
    }
    // writeback dense feats 0..255 (+tower bias, no relu) into densefrag
    const float* bt = t ? bu : bm;
#pragma unroll
    for (int s = 0; s < 2; ++s) {
      const int ft = w + s * 8;
      const int fb = ft * 16 + q * 4;      // feature strip start (4 consecutive)
      const float g0 = bt[fb], g1 = bt[fb + 1], g2 = bt[fb + 2], g3 = bt[fb + 3];
      const int kd = t * 256 + fb;         // all_dense k index
      const int ksd = kd >> 5, qd = (kd >> 3) & 3, ed = kd & 4;
#pragma unroll
      for (int rt = 0; rt < 4; ++rt) {
        const f32x4 v = accA[s][rt];
        uint2 p;
        p.x = f2bf(v[0] + g0) | ((unsigned)f2bf(v[1] + g1) << 16);
        p.y = f2bf(v[2] + g2) | ((unsigned)f2bf(v[3] + g3) << 16);
        *(uint2*)(densefrag + (((ksd * 4 + rt) * 64 + qd * 16 + cn) << 4) +
                  (ed ? 8 : 0)) = p;
      }
    }
  }

  // ---------------- FM: sum(interactions) = <ms, us>; plus additive term
  if (w < 4) {
    float p = 0.f;
#pragma unroll
    for (int reg = 0; reg < 4; ++reg) {
      const float msv = accM[reg] + auxb[q * 4 + reg];
      const float usv = accU[reg] + auxb[16 + q * 4 + reg];
      p += msv * usv;
    }
    p += __shfl_xor(p, 16, 64);
    p += __shfl_xor(p, 32, 64);
    if (l < 16) atomicAdd(&outpart[w * 16 + cn], p);
  } else if (q == 0) {
    // lane(q=0) reg0 of ft17 tile = feature 272 (additive), both towers summed
    atomicAdd(&outpart[(w - 4) * 16 + cn], accM[0] + auxb[32]);
  }

  // ---------------- Phase 2: h1 = relu(all_dense @ W1 + b1)
#pragma unroll
  for (int s = 0; s < 2; ++s)
#pragma unroll
    for (int rt = 0; rt < 4; ++rt) accA[s][rt] = zz;
  {
    const char* W1F = ws + WS_W1F;
    for (int c = 0; c < 8; ++c) {
      __syncthreads();
      const uint4* g = (const uint4*)(W1F + c * 32768);
      uint4* d = (uint4*)wbuf;
      for (int j = tid; j < 2048; j += NTH) d[j] = g[j];
      __syncthreads();
#pragma unroll
      for (int ks = 0; ks < 2; ++ks) {
        const int kg = c * 2 + ks;
        bf16x8 bfr[4];
#pragma unroll
        for (int rt = 0; rt < 4; ++rt)
          bfr[rt] = *(const bf16x8*)(densefrag + (((kg * 4 + rt) * 64 + l) << 4));
        const bf16x8 a0 = *(const bf16x8*)(wbuf + (((ks * 16 + w) * 64 + l) << 4));
        const bf16x8 a1 = *(const bf16x8*)(wbuf + (((ks * 16 + w + 8) * 64 + l) << 4));
#pragma unroll
        for (int rt = 0; rt < 4; ++rt) accA[0][rt] = mfma_bf16(a0, bfr[rt], accA[0][rt]);
#pragma unroll
        for (int rt = 0; rt < 4; ++rt) accA[1][rt] = mfma_bf16(a1, bfr[rt], accA[1][rt]);
      }
    }
#pragma unroll
    for (int s = 0; s < 2; ++s) {
      const int ft = w + s * 8;
      const int fb = ft * 16 + q * 4;
      const float g0 = b1[fb], g1 = b1[fb + 1], g2 = b1[fb + 2], g3 = b1[fb + 3];
      const int ksd = fb >> 5, qd = (fb >> 3) & 3, ed = fb & 4;
#pragma unroll
      for (int rt = 0; rt < 4; ++rt) {
        const f32x4 v = accA[s][rt];
        uint2 p;
        p.x = f2bf(fmaxf(v[0] + g0, 0.f)) | ((unsigned)f2bf(fmaxf(v[1] + g1, 0.f)) << 16);
        p.y = f2bf(fmaxf(v[2] + g2, 0.f)) | ((unsigned)f2bf(fmaxf(v[3] + g3, 0.f)) << 16);
        *(uint2*)(h1frag + (((ksd * 4 + rt) * 64 + qd * 16 + cn) << 4) +
                  (ed ? 8 : 0)) = p;
      }
    }
  }

  // ---------------- Phase 3: h2 = relu(h1 @ W2 + b2); out = h2 @ W3 (+FM)
  {
    f32x4 acc3[4] = {zz, zz, zz, zz};
    const char* W2F = ws + WS_W2F;
    for (int c = 0; c < 4; ++c) {
      __syncthreads();
      const uint4* g = (const uint4*)(W2F + c * 16384);
      uint4* d = (uint4*)wbuf;
      for (int j = tid; j < 1024; j += NTH) d[j] = g[j];
      __syncthreads();
#pragma unroll
      for (int ks = 0; ks < 2; ++ks) {
        const int kg = c * 2 + ks;
        bf16x8 bfr[4];
#pragma unroll
        for (int rt = 0; rt < 4; ++rt)
          bfr[rt] = *(const bf16x8*)(h1frag + (((kg * 4 + rt) * 64 + l) << 4));
        const bf16x8 a0 = *(const bf16x8*)(wbuf + (((ks * 8 + w) * 64 + l) << 4));
#pragma unroll
        for (int rt = 0; rt < 4; ++rt) acc3[rt] = mfma_bf16(a0, bfr[rt], acc3[rt]);
      }
    }
    const int fb = w * 16 + q * 4;       // h2 feature strip (0..127)
    float bb[4], ww[4];
#pragma unroll
    for (int i = 0; i < 4; ++i) { bb[i] = b2[fb + i]; ww[i] = W3[fb + i]; }
#pragma unroll
    for (int rt = 0; rt < 4; ++rt) {
      float p = 0.f;
#pragma unroll
      for (int reg = 0; reg < 4; ++reg)
        p += fmaxf(acc3[rt][reg] + bb[reg], 0.f) * ww[reg];
      p += __shfl_xor(p, 16, 64);
      p += __shfl_xor(p, 32, 64);
      if (l < 16) atomicAdd(&outpart[rt * 16 + cn], p);
    }
  }

  __syncthreads();
  if (tid < 64) out[row0 + tid] = outpart[tid];
}

// ---------------------------------------------------------------------------
extern "C" void kernel_launch(void* const* d_in, const int* in_sizes, int n_in,
                              void* d_out, int out_size, void* d_ws, size_t ws_size,
                              hipStream_t stream) {
  const float* movie = (const float*)d_in[0];
  const float* user  = (const float*)d_in[1];
  const float* Wm = (const float*)d_in[2];
  const float* bm = (const float*)d_in[3];
  const float* Wu = (const float*)d_in[4];
  const float* bu = (const float*)d_in[5];
  const float* W1 = (const float*)d_in[6];
  const float* b1 = (const float*)d_in[7];
  const float* W2 = (const float*)d_in[8];
  const float* b2 = (const float*)d_in[9];
  const float* W3 = (const float*)d_in[10];
  const float* b3 = (const float*)d_in[11];
  char* ws = (char*)d_ws;
  float* out = (float*)d_out;

  // allow >64KB dynamic LDS (idempotent; not a stream op, capture-safe)
  (void)hipFuncSetAttribute((const void*)deepfm_main,
                            hipFuncAttributeMaxDynamicSharedMemorySize, LDS_BYTES);

  deepfm_prep<<<897, 64, 0, stream>>>(Wm, bm, Wu, bu, W1, W2, b3, ws);
  deepfm_main<<<256, NTH, LDS_BYTES, stream>>>(movie, user, bm, bu, b1, b2, W3, ws, out);
}

// Round 2
// 207.456 us; speedup vs baseline: 1.0530x; 1.0530x over previous
//
#include <hip/hip_runtime.h>

// DeepFM fused kernel for MI355X (gfx950) — round 2.
//  - prep1: FM column sums (colsums[t][k][16]) massively parallel.
//  - prep2: repack Wm/Wu (augmented w/ FM sum cols + additive), W1, W2 into
//    bf16 MFMA A-frag order in ws; bias aux.
//  - cvt:   movie/user fp32 -> bf16 B-frag order in ws (BW-bound).
//  - main:  256 blocks x 512 thr, 64 rows/block. A- and B-frags loaded
//    DIRECTLY global->register (coalesced 1KB/wave, L2/L3-resident);
//    LDS only for inter-phase dense/h1 frags. 3 barriers total.

#define RB  64
#define NTH 512

typedef __bf16 bf16x8 __attribute__((ext_vector_type(8)));
typedef float  f32x4  __attribute__((ext_vector_type(4)));

// workspace layout (bytes)
#define WS_WMF  0            // movie tower A-frags [16 ks][18 ft][64][16B]
#define WS_WUF  294912
#define WS_W1F  589824       // [16 ks][16 ft][64][16B]
#define WS_W2F  851968       // [8 ks][8 ft][64][16B]
#define WS_BIAS 917504       // fp32 bms[16] bus[16] badd
#define WS_CS   917760       // fp32 colsums [2][512][16] = 65536
#define WS_INF  983296       // bf16 input B-frags [2][256 b][8 c][2 ks][4 rt][64][16B]
#define WS_END  (983296 + 33554432)

__device__ __forceinline__ unsigned short f2bf(float f) {
  unsigned u = __builtin_bit_cast(unsigned, f);
  u += 0x7FFFu + ((u >> 16) & 1u);
  return (unsigned short)(u >> 16);
}

__device__ __forceinline__ f32x4 mfma_bf16(bf16x8 a, bf16x8 b, f32x4 c) {
  return __builtin_amdgcn_mfma_f32_16x16x32_bf16(a, b, c, 0, 0, 0);
}

// ---------------------------------------------------------------------------
extern "C" __global__ __launch_bounds__(256) void deepfm_prep1(
    const float* __restrict__ Wm, const float* __restrict__ Wu,
    char* __restrict__ ws) {
  const int id = blockIdx.x * 256 + threadIdx.x;   // [2][512][16]
  const int t = id >> 13, k = (id >> 4) & 511, c = id & 15;
  const float* W = t ? Wu : Wm;
  float s = 0.f;
#pragma unroll
  for (int i = 0; i < 16; ++i) s += W[k * 257 + i * 16 + c];
  ((float*)(ws + WS_CS))[id] = s;
}

// ---------------------------------------------------------------------------
extern "C" __global__ __launch_bounds__(64) void deepfm_prep2(
    const float* __restrict__ Wm, const float* __restrict__ bm,
    const float* __restrict__ Wu, const float* __restrict__ bu,
    const float* __restrict__ W1, const float* __restrict__ W2,
    const float* __restrict__ b3, char* __restrict__ ws) {
  const int bid = blockIdx.x;
  const int l = threadIdx.x;
  const int fi = l & 15, q = l >> 4;
  unsigned short h[8];
  if (bid < 576) {                       // towers: 2 x 16 ks x 18 ft
    const int t = bid / 288, rem = bid % 288;
    const int ks = rem / 18, ft = rem % 18;
    const float* W = t ? Wu : Wm;
    const float* CS = (const float*)(ws + WS_CS);
    char* outp = ws + (t ? WS_WUF : WS_WMF);
    const int f = ft * 16 + fi;
#pragma unroll
    for (int e = 0; e < 8; ++e) {
      const int k = ks * 32 + q * 8 + e;
      float val;
      if (f < 256) val = W[k * 257 + f];
      else if (f < 272) val = CS[(t * 512 + k) * 16 + (f - 256)];
      else if (f == 272) val = W[k * 257 + 256];
      else val = 0.f;
      h[e] = f2bf(val);
    }
    uint4 o;
    o.x = h[0] | ((unsigned)h[1] << 16); o.y = h[2] | ((unsigned)h[3] << 16);
    o.z = h[4] | ((unsigned)h[5] << 16); o.w = h[6] | ((unsigned)h[7] << 16);
    *(uint4*)(outp + (((ks * 18 + ft) * 64 + l) << 4)) = o;
  } else if (bid < 832) {                // W1: 16 ks x 16 ft
    const int bb = bid - 576;
    const int ks = bb / 16, ft = bb % 16;
    const int f = ft * 16 + fi;
#pragma unroll
    for (int e = 0; e < 8; ++e) h[e] = f2bf(W1[(ks * 32 + q * 8 + e) * 256 + f]);
    uint4 o;
    o.x = h[0] | ((unsigned)h[1] << 16); o.y = h[2] | ((unsigned)h[3] << 16);
    o.z = h[4] | ((unsigned)h[5] << 16); o.w = h[6] | ((unsigned)h[7] << 16);
    *(uint4*)(ws + WS_W1F + (((ks * 16 + ft) * 64 + l) << 4)) = o;
  } else if (bid < 896) {                // W2: 8 ks x 8 ft
    const int bb = bid - 832;
    const int ks = bb / 8, ft = bb % 8;
    const int f = ft * 16 + fi;
#pragma unroll
    for (int e = 0; e < 8; ++e) h[e] = f2bf(W2[(ks * 32 + q * 8 + e) * 128 + f]);
    uint4 o;
    o.x = h[0] | ((unsigned)h[1] << 16); o.y = h[2] | ((unsigned)h[3] << 16);
    o.z = h[4] | ((unsigned)h[5] << 16); o.w = h[6] | ((unsigned)h[7] << 16);
    *(uint4*)(ws + WS_W2F + (((ks * 8 + ft) * 64 + l) << 4)) = o;
  } else {                               // bias aux
    float* aux = (float*)(ws + WS_BIAS);
    if (l < 16) {
      float s = 0.f;
      for (int i = 0; i < 16; ++i) s += bm[i * 16 + l];
      aux[l] = s;
    } else if (l < 32) {
      const int k = l - 16;
      float s = 0.f;
      for (int i = 0; i < 16; ++i) s += bu[i * 16 + k];
      aux[l] = s;
    } else if (l == 32) {
      aux[32] = bm[256] + bu[256] + b3[0];
    }
  }
}

// ---------------------------------------------------------------------------
// Input fp32 -> bf16 B-frag layout. One wave per frag (64 x 16B = 1KB out).
// frag id = (((t*256 + b)*8 + c)*2 + ks)*4 + rt; lane l = q*16 + n:
//   row = b*64 + rt*16 + n; k = c*64 + ks*32 + q*8 + e.
// ---------------------------------------------------------------------------
extern "C" __global__ __launch_bounds__(256) void deepfm_cvt(
    const float* __restrict__ movie, const float* __restrict__ user,
    char* __restrict__ ws) {
  const int fid = blockIdx.x * 4 + (threadIdx.x >> 6);
  const int l = threadIdx.x & 63;
  const int rt = fid & 3, ks = (fid >> 2) & 1, c = (fid >> 3) & 7;
  const int b = (fid >> 6) & 255, t = fid >> 14;
  const float* inp = t ? user : movie;
  const int row = b * 64 + rt * 16 + (l & 15);
  const int k0 = c * 64 + ks * 32 + (l >> 4) * 8;
  const float4 v0 = *(const float4*)(inp + (size_t)row * 512 + k0);
  const float4 v1 = *(const float4*)(inp + (size_t)row * 512 + k0 + 4);
  uint4 o;
  o.x = f2bf(v0.x) | ((unsigned)f2bf(v0.y) << 16);
  o.y = f2bf(v0.z) | ((unsigned)f2bf(v0.w) << 16);
  o.z = f2bf(v1.x) | ((unsigned)f2bf(v1.y) << 16);
  o.w = f2bf(v1.z) | ((unsigned)f2bf(v1.w) << 16);
  *(uint4*)(ws + WS_INF + (((size_t)fid * 64 + l) << 4)) = o;
}

// ---------------------------------------------------------------------------
// Main fused kernel. GF=true: B-frags from global fragbuf (no in-loop sync).
// GF=false: convert inputs in LDS per chunk (fallback if ws too small).
// LDS: densefrag 65536 | h1frag 32768 | outpart 256 | [infrag 8192 GF=false]
// ---------------------------------------------------------------------------
template <bool GF>
__global__ __launch_bounds__(NTH, 1) void deepfm_main_t(
    const float* __restrict__ movie, const float* __restrict__ user,
    const float* __restrict__ bm, const float* __restrict__ bu,
    const float* __restrict__ b1, const float* __restrict__ b2,
    const float* __restrict__ W3, const char* __restrict__ ws,
    const char* __restrict__ fragbuf, float* __restrict__ out) {
  extern __shared__ __align__(16) char lds[];
  char* const densefrag = lds;             // [16 kg][4 rt][64][16]
  char* const h1frag    = lds + 65536;     // [8 kg][4 rt][64][16]
  float* const outpart  = (float*)(lds + 98304);
  char* const infrag    = lds + 98560;     // GF=false only

  const int tid = threadIdx.x;
  const int w   = tid >> 6;
  const int l   = tid & 63;
  const int cn  = l & 15;
  const int q   = l >> 4;
  const int row0 = blockIdx.x * RB;
  const int auxrt = w & 3;

  if (tid < 64) outpart[tid] = 0.f;

  const f32x4 zz = {0.f, 0.f, 0.f, 0.f};
  f32x4 accA[2][4];
  f32x4 accM = zz, accU = zz;
  const float* auxb = (const float*)(ws + WS_BIAS);

  // ---------------- Phase 1: towers
  for (int t = 0; t < 2; ++t) {
    const char* WF = ws + (t ? WS_WUF : WS_WMF);
    const char* FB = fragbuf + (((size_t)t * 256 + blockIdx.x) << 16);
    const float* inp = t ? user : movie;
#pragma unroll
    for (int s = 0; s < 2; ++s)
#pragma unroll
      for (int rt = 0; rt < 4; ++rt) accA[s][rt] = zz;

    for (int c = 0; c < 8; ++c) {
      if (!GF) {
        __syncthreads();
        for (int j = tid; j < 1024; j += NTH) {
          const int r = j >> 4, k4 = j & 15;
          const float4 v = *(const float4*)(inp + (size_t)(row0 + r) * 512 + c * 64 + k4 * 4);
          const int kl = k4 * 4;
          const int ks = kl >> 5, qq = (kl >> 3) & 3;
          uint2 p;
          p.x = f2bf(v.x) | ((unsigned)f2bf(v.y) << 16);
          p.y = f2bf(v.z) | ((unsigned)f2bf(v.w) << 16);
          *(uint2*)(infrag + (((ks * 4 + (r >> 4)) * 64 + qq * 16 + (r & 15)) << 4) +
                    ((kl & 4) ? 8 : 0)) = p;
        }
        __syncthreads();
      }
#pragma unroll
      for (int ks = 0; ks < 2; ++ks) {
        const int kg = c * 2 + ks;
        bf16x8 bfr[4];
#pragma unroll
        for (int rt = 0; rt < 4; ++rt) {
          if (GF) bfr[rt] = *(const bf16x8*)(FB + (((kg * 4 + rt) * 64 + l) << 4));
          else    bfr[rt] = *(const bf16x8*)(infrag + (((ks * 4 + rt) * 64 + l) << 4));
        }
        const bf16x8 a0 = *(const bf16x8*)(WF + (((kg * 18 + w) * 64 + l) << 4));
        const bf16x8 a1 = *(const bf16x8*)(WF + (((kg * 18 + w + 8) * 64 + l) << 4));
        const bf16x8 ax = *(const bf16x8*)(WF + (((kg * 18 + (w < 4 ? 16 : 17)) * 64 + l) << 4));
#pragma unroll
        for (int rt = 0; rt < 4; ++rt) accA[0][rt] = mfma_bf16(a0, bfr[rt], accA[0][rt]);
#pragma unroll
        for (int rt = 0; rt < 4; ++rt) accA[1][rt] = mfma_bf16(a1, bfr[rt], accA[1][rt]);
        if (w < 4) {
          if (t == 0) accM = mfma_bf16(ax, bfr[auxrt], accM);
          else        accU = mfma_bf16(ax, bfr[auxrt], accU);
        } else {
          accM = mfma_bf16(ax, bfr[auxrt], accM);
        }
      }
    }
    const float* bt = t ? bu : bm;
#pragma unroll
    for (int s = 0; s < 2; ++s) {
      const int ft = w + s * 8;
      const int fb = ft * 16 + q * 4;
      const float g0 = bt[fb], g1 = bt[fb + 1], g2 = bt[fb + 2], g3 = bt[fb + 3];
      const int kd = t * 256 + fb;
      const int ksd = kd >> 5, qd = (kd >> 3) & 3, ed = kd & 4;
#pragma unroll
      for (int rt = 0; rt < 4; ++rt) {
        const f32x4 v = accA[s][rt];
        uint2 p;
        p.x = f2bf(v[0] + g0) | ((unsigned)f2bf(v[1] + g1) << 16);
        p.y = f2bf(v[2] + g2) | ((unsigned)f2bf(v[3] + g3) << 16);
        *(uint2*)(densefrag + (((ksd * 4 + rt) * 64 + qd * 16 + cn) << 4) +
                  (ed ? 8 : 0)) = p;
      }
    }
  }

  __syncthreads();   // densefrag complete; outpart init visible

  // ---------------- FM
  if (w < 4) {
    float p = 0.f;
#pragma unroll
    for (int reg = 0; reg < 4; ++reg) {
      const float msv = accM[reg] + auxb[q * 4 + reg];
      const float usv = accU[reg] + auxb[16 + q * 4 + reg];
      p += msv * usv;
    }
    p += __shfl_xor(p, 16, 64);
    p += __shfl_xor(p, 32, 64);
    if (l < 16) atomicAdd(&outpart[w * 16 + cn], p);
  } else if (q == 0) {
    atomicAdd(&outpart[(w - 4) * 16 + cn], accM[0] + auxb[32]);
  }

  // ---------------- Phase 2: h1 = relu(all_dense @ W1 + b1)
#pragma unroll
  for (int s = 0; s < 2; ++s)
#pragma unroll
    for (int rt = 0; rt < 4; ++rt) accA[s][rt] = zz;
  {
    const char* W1F = ws + WS_W1F;
    for (int c = 0; c < 8; ++c) {
#pragma unroll
      for (int ks = 0; ks < 2; ++ks) {
        const int kg = c * 2 + ks;
        bf16x8 bfr[4];
#pragma unroll
        for (int rt = 0; rt < 4; ++rt)
          bfr[rt] = *(const bf16x8*)(densefrag + (((kg * 4 + rt) * 64 + l) << 4));
        const bf16x8 a0 = *(const bf16x8*)(W1F + (((kg * 16 + w) * 64 + l) << 4));
        const bf16x8 a1 = *(const bf16x8*)(W1F + (((kg * 16 + w + 8) * 64 + l) << 4));
#pragma unroll
        for (int rt = 0; rt < 4; ++rt) accA[0][rt] = mfma_bf16(a0, bfr[rt], accA[0][rt]);
#pragma unroll
        for (int rt = 0; rt < 4; ++rt) accA[1][rt] = mfma_bf16(a1, bfr[rt], accA[1][rt]);
      }
    }
#pragma unroll
    for (int s = 0; s < 2; ++s) {
      const int ft = w + s * 8;
      const int fb = ft * 16 + q * 4;
      const float g0 = b1[fb], g1 = b1[fb + 1], g2 = b1[fb + 2], g3 = b1[fb + 3];
      const int ksd = fb >> 5, qd = (fb >> 3) & 3, ed = fb & 4;
#pragma unroll
      for (int rt = 0; rt < 4; ++rt) {
        const f32x4 v = accA[s][rt];
        uint2 p;
        p.x = f2bf(fmaxf(v[0] + g0, 0.f)) | ((unsigned)f2bf(fmaxf(v[1] + g1, 0.f)) << 16);
        p.y = f2bf(fmaxf(v[2] + g2, 0.f)) | ((unsigned)f2bf(fmaxf(v[3] + g3, 0.f)) << 16);
        *(uint2*)(h1frag + (((ksd * 4 + rt) * 64 + qd * 16 + cn) << 4) +
                  (ed ? 8 : 0)) = p;
      }
    }
  }

  __syncthreads();   // h1frag complete

  // ---------------- Phase 3: h2 = relu(h1 @ W2 + b2); out = h2 @ W3
  {
    f32x4 acc3[4] = {zz, zz, zz, zz};
    const char* W2F = ws + WS_W2F;
    for (int c = 0; c < 4; ++c) {
#pragma unroll
      for (int ks = 0; ks < 2; ++ks) {
        const int kg = c * 2 + ks;
        bf16x8 bfr[4];
#pragma unroll
        for (int rt = 0; rt < 4; ++rt)
          bfr[rt] = *(const bf16x8*)(h1frag + (((kg * 4 + rt) * 64 + l) << 4));
        const bf16x8 a0 = *(const bf16x8*)(W2F + (((kg * 8 + w) * 64 + l) << 4));
#pragma unroll
        for (int rt = 0; rt < 4; ++rt) acc3[rt] = mfma_bf16(a0, bfr[rt], acc3[rt]);
      }
    }
    const int fb = w * 16 + q * 4;
    float bb[4], ww[4];
#pragma unroll
    for (int i = 0; i < 4; ++i) { bb[i] = b2[fb + i]; ww[i] = W3[fb + i]; }
#pragma unroll
    for (int rt = 0; rt < 4; ++rt) {
      float p = 0.f;
#pragma unroll
      for (int reg = 0; reg < 4; ++reg)
        p += fmaxf(acc3[rt][reg] + bb[reg], 0.f) * ww[reg];
      p += __shfl_xor(p, 16, 64);
      p += __shfl_xor(p, 32, 64);
      if (l < 16) atomicAdd(&outpart[rt * 16 + cn], p);
    }
  }

  __syncthreads();
  if (tid < 64) out[row0 + tid] = outpart[tid];
}

// ---------------------------------------------------------------------------
extern "C" void kernel_launch(void* const* d_in, const int* in_sizes, int n_in,
                              void* d_out, int out_size, void* d_ws, size_t ws_size,
                              hipStream_t stream) {
  const float* movie = (const float*)d_in[0];
  const float* user  = (const float*)d_in[1];
  const float* Wm = (const float*)d_in[2];
  const float* bm = (const float*)d_in[3];
  const float* Wu = (const float*)d_in[4];
  const float* bu = (const float*)d_in[5];
  const float* W1 = (const float*)d_in[6];
  const float* b1 = (const float*)d_in[7];
  const float* W2 = (const float*)d_in[8];
  const float* b2 = (const float*)d_in[9];
  const float* W3 = (const float*)d_in[10];
  const float* b3 = (const float*)d_in[11];
  char* ws = (char*)d_ws;
  float* out = (float*)d_out;

  (void)hipFuncSetAttribute(reinterpret_cast<const void*>(&deepfm_main_t<true>),
                            hipFuncAttributeMaxDynamicSharedMemorySize, 98560);
  (void)hipFuncSetAttribute(reinterpret_cast<const void*>(&deepfm_main_t<false>),
                            hipFuncAttributeMaxDynamicSharedMemorySize, 106752);

  deepfm_prep1<<<64, 256, 0, stream>>>(Wm, Wu, ws);
  deepfm_prep2<<<897, 64, 0, stream>>>(Wm, bm, Wu, bu, W1, W2, b3, ws);

  if (ws_size >= (size_t)WS_END) {
    deepfm_cvt<<<8192, 256, 0, stream>>>(movie, user, ws);
    deepfm_main_t<true><<<256, NTH, 98560, stream>>>(
        movie, user, bm, bu, b1, b2, W3, ws, ws + WS_INF, out);
  } else {
    deepfm_main_t<false><<<256, NTH, 106752, stream>>>(
        movie, user, bm, bu, b1, b2, W3, ws, ws, out);
  }
}

// Round 4
// 181.863 us; speedup vs baseline: 1.2011x; 1.1407x over previous
//
#include <hip/hip_runtime.h>

// DeepFM fused kernel for MI355X (gfx950) — round 4 (bisect of round 3).
//  - prep1: FM column sums (colsums[t][k][16]).
//  - prep2: repack Wm/Wu (augmented with FM sum cols + additive), W1, W2 into
//    bf16 MFMA A-frag order in ws; bias aux.
//  - main:  512 blocks x 512 thr (8 waves), 32 rows/block, 2 blocks/CU
//    (static LDS 48.5 KB). B operand: fp32 loaded directly from HBM
//    (2 contiguous float4 per lane), converted in-register to bf16.
//    A operand: frag-ordered bf16 from ws (L2/L3-resident), coalesced
//    1KB/wave loads. NO manual double-buffering (round-3 suspect) —
//    plain loops, loads feed MFMAs directly, compiler schedules.

#define NTH 512
#define RB  32

typedef __bf16 bf16x8 __attribute__((ext_vector_type(8)));
typedef float  f32x4  __attribute__((ext_vector_type(4)));
typedef unsigned short u16x8 __attribute__((ext_vector_type(8)));

// workspace layout (bytes)
#define WS_WMF  0            // movie tower A-frags [16 kg][18 ft][64][16B]
#define WS_WUF  294912
#define WS_W1F  589824       // [16 kg][16 ft][64][16B]
#define WS_W2F  851968       // [8 kg][8 ft][64][16B]
#define WS_BIAS 917504       // fp32 bms[16] bus[16] badd
#define WS_CS   917760       // fp32 colsums [2][512][16] = 65536

__device__ __forceinline__ unsigned short f2bf(float f) {
  unsigned u = __builtin_bit_cast(unsigned, f);
  u += 0x7FFFu + ((u >> 16) & 1u);           // RNE
  return (unsigned short)(u >> 16);
}

__device__ __forceinline__ bf16x8 cvt8(float4 a, float4 b) {
  u16x8 t;
  t[0] = f2bf(a.x); t[1] = f2bf(a.y); t[2] = f2bf(a.z); t[3] = f2bf(a.w);
  t[4] = f2bf(b.x); t[5] = f2bf(b.y); t[6] = f2bf(b.z); t[7] = f2bf(b.w);
  return __builtin_bit_cast(bf16x8, t);
}

__device__ __forceinline__ f32x4 mfma_bf16(bf16x8 a, bf16x8 b, f32x4 c) {
  return __builtin_amdgcn_mfma_f32_16x16x32_bf16(a, b, c, 0, 0, 0);
}

// ---------------------------------------------------------------------------
extern "C" __global__ __launch_bounds__(256) void deepfm_prep1(
    const float* __restrict__ Wm, const float* __restrict__ Wu,
    char* __restrict__ ws) {
  const int id = blockIdx.x * 256 + threadIdx.x;   // [2][512][16]
  const int t = id >> 13, k = (id >> 4) & 511, c = id & 15;
  const float* W = t ? Wu : Wm;
  float s = 0.f;
#pragma unroll
  for (int i = 0; i < 16; ++i) s += W[k * 257 + i * 16 + c];
  ((float*)(ws + WS_CS))[id] = s;
}

// ---------------------------------------------------------------------------
extern "C" __global__ __launch_bounds__(64) void deepfm_prep2(
    const float* __restrict__ Wm, const float* __restrict__ bm,
    const float* __restrict__ Wu, const float* __restrict__ bu,
    const float* __restrict__ W1, const float* __restrict__ W2,
    const float* __restrict__ b3, char* __restrict__ ws) {
  const int bid = blockIdx.x;
  const int l = threadIdx.x;
  const int fi = l & 15, q = l >> 4;
  unsigned short h[8];
  if (bid < 576) {                       // towers: 2 x 16 kg x 18 ft
    const int t = bid / 288, rem = bid % 288;
    const int kg = rem / 18, ft = rem % 18;
    const float* W = t ? Wu : Wm;
    const float* CS = (const float*)(ws + WS_CS);
    char* outp = ws + (t ? WS_WUF : WS_WMF);
    const int f = ft * 16 + fi;
#pragma unroll
    for (int e = 0; e < 8; ++e) {
      const int k = kg * 32 + q * 8 + e;
      float val;
      if (f < 256) val = W[k * 257 + f];
      else if (f < 272) val = CS[(t * 512 + k) * 16 + (f - 256)];
      else if (f == 272) val = W[k * 257 + 256];
      else val = 0.f;
      h[e] = f2bf(val);
    }
    uint4 o;
    o.x = h[0] | ((unsigned)h[1] << 16); o.y = h[2] | ((unsigned)h[3] << 16);
    o.z = h[4] | ((unsigned)h[5] << 16); o.w = h[6] | ((unsigned)h[7] << 16);
    *(uint4*)(outp + (((kg * 18 + ft) * 64 + l) << 4)) = o;
  } else if (bid < 832) {                // W1: 16 kg x 16 ft
    const int bb = bid - 576;
    const int kg = bb / 16, ft = bb % 16;
    const int f = ft * 16 + fi;
#pragma unroll
    for (int e = 0; e < 8; ++e) h[e] = f2bf(W1[(kg * 32 + q * 8 + e) * 256 + f]);
    uint4 o;
    o.x = h[0] | ((unsigned)h[1] << 16); o.y = h[2] | ((unsigned)h[3] << 16);
    o.z = h[4] | ((unsigned)h[5] << 16); o.w = h[6] | ((unsigned)h[7] << 16);
    *(uint4*)(ws + WS_W1F + (((kg * 16 + ft) * 64 + l) << 4)) = o;
  } else if (bid < 896) {                // W2: 8 kg x 8 ft
    const int bb = bid - 832;
    const int kg = bb / 8, ft = bb % 8;
    const int f = ft * 16 + fi;
#pragma unroll
    for (int e = 0; e < 8; ++e) h[e] = f2bf(W2[(kg * 32 + q * 8 + e) * 128 + f]);
    uint4 o;
    o.x = h[0] | ((unsigned)h[1] << 16); o.y = h[2] | ((unsigned)h[3] << 16);
    o.z = h[4] | ((unsigned)h[5] << 16); o.w = h[6] | ((unsigned)h[7] << 16);
    *(uint4*)(ws + WS_W2F + (((kg * 8 + ft) * 64 + l) << 4)) = o;
  } else {                               // bias aux
    float* aux = (float*)(ws + WS_BIAS);
    if (l < 16) {
      float s = 0.f;
      for (int i = 0; i < 16; ++i) s += bm[i * 16 + l];
      aux[l] = s;
    } else if (l < 32) {
      const int k = l - 16;
      float s = 0.f;
      for (int i = 0; i < 16; ++i) s += bu[i * 16 + k];
      aux[l] = s;
    } else if (l == 32) {
      aux[32] = bm[256] + bu[256] + b3[0];
    }
  }
}

// ---------------------------------------------------------------------------
// Main fused kernel. 32 rows/block, 8 waves. Wave w: tower ft tiles {w, w+8}
// (+aux ft16 on waves 0,1 / ft17 on waves 4,5), rt in {0,1}.
// LDS: densefrag [16kg][2rt][64][16] 32KB | h1frag [8kg][2rt][64][16] 16KB
//      | outpart[32].  Total 48.5 KB -> 2 blocks/CU.
// ---------------------------------------------------------------------------
extern "C" __global__ __launch_bounds__(NTH, 4) void deepfm_main(
    const float* __restrict__ movie, const float* __restrict__ user,
    const float* __restrict__ bm, const float* __restrict__ bu,
    const float* __restrict__ b1, const float* __restrict__ b2,
    const float* __restrict__ W3, const char* __restrict__ ws,
    float* __restrict__ out) {
  __shared__ __align__(16) char densefrag[32768];
  __shared__ __align__(16) char h1frag[16384];
  __shared__ float outpart[32];

  const int tid = threadIdx.x;
  const int w   = tid >> 6;
  const int l   = tid & 63;
  const int cn  = l & 15;
  const int q   = l >> 4;
  const int row0 = blockIdx.x * RB;

  const bool doAux = (w < 2) || (w == 4) || (w == 5);
  const int  axrt  = (w < 2) ? w : (w - 4);     // rt tile for aux MFMA
  const int  axi   = (w >= 4) ? 1 : 0;          // ft16 (ms/us) vs ft17 (additive)

  if (tid < 32) outpart[tid] = 0.f;

  const f32x4 zz = {0.f, 0.f, 0.f, 0.f};
  f32x4 accA[2][2];
  f32x4 accM = zz, accU = zz;
  const float* auxb = (const float*)(ws + WS_BIAS);

  // ---------------- Phase 1: towers
  for (int t = 0; t < 2; ++t) {
    const float* inp = t ? user : movie;
    const char* WF = ws + (t ? WS_WUF : WS_WMF);
    accA[0][0] = zz; accA[0][1] = zz; accA[1][0] = zz; accA[1][1] = zz;

    const float* rbase = inp + (size_t)(row0 + cn) * 512 + q * 8;

    for (int kg = 0; kg < 16; ++kg) {
      const float* rp = rbase + kg * 32;
      const float4 b00 = *(const float4*)(rp);
      const float4 b01 = *(const float4*)(rp + 4);
      const float4 b10 = *(const float4*)(rp + 16 * 512);
      const float4 b11 = *(const float4*)(rp + 16 * 512 + 4);
      const bf16x8 a0 = *(const bf16x8*)(WF + (((kg * 18 + w) * 64 + l) << 4));
      const bf16x8 a1 = *(const bf16x8*)(WF + (((kg * 18 + w + 8) * 64 + l) << 4));
      const bf16x8 bf0 = cvt8(b00, b01);
      const bf16x8 bf1 = cvt8(b10, b11);
      accA[0][0] = mfma_bf16(a0, bf0, accA[0][0]);
      accA[0][1] = mfma_bf16(a0, bf1, accA[0][1]);
      accA[1][0] = mfma_bf16(a1, bf0, accA[1][0]);
      accA[1][1] = mfma_bf16(a1, bf1, accA[1][1]);
      if (doAux) {
        const bf16x8 ax = *(const bf16x8*)(WF + (((kg * 18 + 16 + axi) * 64 + l) << 4));
        const bf16x8 bsel = axrt ? bf1 : bf0;
        if (w < 2) {
          if (t == 0) accM = mfma_bf16(ax, bsel, accM);
          else        accU = mfma_bf16(ax, bsel, accU);
        } else {
          accM = mfma_bf16(ax, bsel, accM);   // additive: both towers
        }
      }
    }
    // writeback dense feats (+tower bias, no relu) into densefrag
    const float* bt = t ? bu : bm;
#pragma unroll
    for (int s = 0; s < 2; ++s) {
      const int ft = w + s * 8;
      const int fb = ft * 16 + q * 4;
      const float g0 = bt[fb], g1 = bt[fb + 1], g2 = bt[fb + 2], g3 = bt[fb + 3];
      const int kd = t * 256 + fb;
      const int kgd = kd >> 5, qd = (kd >> 3) & 3, ed = kd & 4;
#pragma unroll
      for (int rt = 0; rt < 2; ++rt) {
        const f32x4 v = accA[s][rt];
        uint2 p;
        p.x = f2bf(v[0] + g0) | ((unsigned)f2bf(v[1] + g1) << 16);
        p.y = f2bf(v[2] + g2) | ((unsigned)f2bf(v[3] + g3) << 16);
        *(uint2*)(densefrag + (((kgd * 2 + rt) * 64 + qd * 16 + cn) << 4) +
                  (ed ? 8 : 0)) = p;
      }
    }
  }

  __syncthreads();   // densefrag complete; outpart init visible

  // ---------------- FM: sum(interactions) = <ms,us>; additive term
  if (w < 2) {
    float p = 0.f;
#pragma unroll
    for (int reg = 0; reg < 4; ++reg) {
      const float msv = accM[reg] + auxb[q * 4 + reg];
      const float usv = accU[reg] + auxb[16 + q * 4 + reg];
      p += msv * usv;
    }
    p += __shfl_xor(p, 16, 64);
    p += __shfl_xor(p, 32, 64);
    if (l < 16) atomicAdd(&outpart[w * 16 + cn], p);
  } else if ((w == 4 || w == 5) && q == 0) {
    atomicAdd(&outpart[(w - 4) * 16 + cn], accM[0] + auxb[32]);
  }

  // ---------------- Phase 2: h1 = relu(all_dense @ W1 + b1)
  accA[0][0] = zz; accA[0][1] = zz; accA[1][0] = zz; accA[1][1] = zz;
  {
    const char* W1F = ws + WS_W1F;
    for (int kg = 0; kg < 16; ++kg) {
      const bf16x8 b0  = *(const bf16x8*)(densefrag + (((kg * 2 + 0) * 64 + l) << 4));
      const bf16x8 b1f = *(const bf16x8*)(densefrag + (((kg * 2 + 1) * 64 + l) << 4));
      const bf16x8 a0 = *(const bf16x8*)(W1F + (((kg * 16 + w) * 64 + l) << 4));
      const bf16x8 a1 = *(const bf16x8*)(W1F + (((kg * 16 + w + 8) * 64 + l) << 4));
      accA[0][0] = mfma_bf16(a0, b0,  accA[0][0]);
      accA[0][1] = mfma_bf16(a0, b1f, accA[0][1]);
      accA[1][0] = mfma_bf16(a1, b0,  accA[1][0]);
      accA[1][1] = mfma_bf16(a1, b1f, accA[1][1]);
    }
#pragma unroll
    for (int s = 0; s < 2; ++s) {
      const int ft = w + s * 8;
      const int fb = ft * 16 + q * 4;
      const float g0 = b1[fb], g1 = b1[fb + 1], g2 = b1[fb + 2], g3 = b1[fb + 3];
      const int kgd = fb >> 5, qd = (fb >> 3) & 3, ed = fb & 4;
#pragma unroll
      for (int rt = 0; rt < 2; ++rt) {
        const f32x4 v = accA[s][rt];
        uint2 p;
        p.x = f2bf(fmaxf(v[0] + g0, 0.f)) | ((unsigned)f2bf(fmaxf(v[1] + g1, 0.f)) << 16);
        p.y = f2bf(fmaxf(v[2] + g2, 0.f)) | ((unsigned)f2bf(fmaxf(v[3] + g3, 0.f)) << 16);
        *(uint2*)(h1frag + (((kgd * 2 + rt) * 64 + qd * 16 + cn) << 4) +
                  (ed ? 8 : 0)) = p;
      }
    }
  }

  __syncthreads();   // h1frag complete

  // ---------------- Phase 3: h2 = relu(h1 @ W2 + b2); out = h2 @ W3 (+FM)
  {
    f32x4 acc3[2] = {zz, zz};
    const char* W2F = ws + WS_W2F;
    for (int kg = 0; kg < 8; ++kg) {
      const bf16x8 b0  = *(const bf16x8*)(h1frag + (((kg * 2 + 0) * 64 + l) << 4));
      const bf16x8 b1f = *(const bf16x8*)(h1frag + (((kg * 2 + 1) * 64 + l) << 4));
      const bf16x8 a0 = *(const bf16x8*)(W2F + (((kg * 8 + w) * 64 + l) << 4));
      acc3[0] = mfma_bf16(a0, b0,  acc3[0]);
      acc3[1] = mfma_bf16(a0, b1f, acc3[1]);
    }
    const int fb = w * 16 + q * 4;       // h2 feature strip (0..127)
    float bb[4], ww[4];
#pragma unroll
    for (int i = 0; i < 4; ++i) { bb[i] = b2[fb + i]; ww[i] = W3[fb + i]; }
#pragma unroll
    for (int rt = 0; rt < 2; ++rt) {
      float p = 0.f;
#pragma unroll
      for (int reg = 0; reg < 4; ++reg)
        p += fmaxf(acc3[rt][reg] + bb[reg], 0.f) * ww[reg];
      p += __shfl_xor(p, 16, 64);
      p += __shfl_xor(p, 32, 64);
      if (l < 16) atomicAdd(&outpart[rt * 16 + cn], p);
    }
  }

  __syncthreads();
  if (tid < 32) out[row0 + tid] = outpart[tid];
}

// ---------------------------------------------------------------------------
extern "C" void kernel_launch(void* const* d_in, const int* in_sizes, int n_in,
                              void* d_out, int out_size, void* d_ws, size_t ws_size,
                              hipStream_t stream) {
  const float* movie = (const float*)d_in[0];
  const float* user  = (const float*)d_in[1];
  const float* Wm = (const float*)d_in[2];
  const float* bm = (const float*)d_in[3];
  const float* Wu = (const float*)d_in[4];
  const float* bu = (const float*)d_in[5];
  const float* W1 = (const float*)d_in[6];
  const float* b1 = (const float*)d_in[7];
  const float* W2 = (const float*)d_in[8];
  const float* b2 = (const float*)d_in[9];
  const float* W3 = (const float*)d_in[10];
  const float* b3 = (const float*)d_in[11];
  char* ws = (char*)d_ws;
  float* out = (float*)d_out;

  deepfm_prep1<<<64, 256, 0, stream>>>(Wm, Wu, ws);
  deepfm_prep2<<<897, 64, 0, stream>>>(Wm, bm, Wu, bu, W1, W2, b3, ws);
  deepfm_main<<<512, NTH, 0, stream>>>(movie, user, bm, bu, b1, b2, W3, ws, out);
}

// Round 5
// 180.535 us; speedup vs baseline: 1.2100x; 1.0074x over previous
//
#include <hip/hip_runtime.h>

// DeepFM fused kernel for MI355X (gfx950) — round 5.
// R4 + ILP: compiler-driven loop unrolling (pragma only; NO manual register
// double-buffering — that was R3's failure mode). Phase-1 kg loop unroll 2
// (~14 loads in flight/wave under the 128-VGPR cap), phases 2/3 unroll 4.
//  - prep1: FM column sums (colsums[t][k][16]).
//  - prep2: repack Wm/Wu (augmented with FM sum cols + additive), W1, W2 into
//    bf16 MFMA A-frag order in ws; bias aux.
//  - main:  512 blocks x 512 thr (8 waves), 32 rows/block, 2 blocks/CU
//    (static LDS 48.5 KB). B: fp32 straight from HBM, cvt in-register.
//    A: frag-ordered bf16 from ws (L2-resident), coalesced 1KB/wave loads.

#define NTH 512
#define RB  32

typedef __bf16 bf16x8 __attribute__((ext_vector_type(8)));
typedef float  f32x4  __attribute__((ext_vector_type(4)));
typedef unsigned short u16x8 __attribute__((ext_vector_type(8)));

// workspace layout (bytes)
#define WS_WMF  0            // movie tower A-frags [16 kg][18 ft][64][16B]
#define WS_WUF  294912
#define WS_W1F  589824       // [16 kg][16 ft][64][16B]
#define WS_W2F  851968       // [8 kg][8 ft][64][16B]
#define WS_BIAS 917504       // fp32 bms[16] bus[16] badd
#define WS_CS   917760       // fp32 colsums [2][512][16] = 65536

__device__ __forceinline__ unsigned short f2bf(float f) {
  unsigned u = __builtin_bit_cast(unsigned, f);
  u += 0x7FFFu + ((u >> 16) & 1u);           // RNE
  return (unsigned short)(u >> 16);
}

__device__ __forceinline__ bf16x8 cvt8(float4 a, float4 b) {
  u16x8 t;
  t[0] = f2bf(a.x); t[1] = f2bf(a.y); t[2] = f2bf(a.z); t[3] = f2bf(a.w);
  t[4] = f2bf(b.x); t[5] = f2bf(b.y); t[6] = f2bf(b.z); t[7] = f2bf(b.w);
  return __builtin_bit_cast(bf16x8, t);
}

__device__ __forceinline__ f32x4 mfma_bf16(bf16x8 a, bf16x8 b, f32x4 c) {
  return __builtin_amdgcn_mfma_f32_16x16x32_bf16(a, b, c, 0, 0, 0);
}

// ---------------------------------------------------------------------------
extern "C" __global__ __launch_bounds__(256) void deepfm_prep1(
    const float* __restrict__ Wm, const float* __restrict__ Wu,
    char* __restrict__ ws) {
  const int id = blockIdx.x * 256 + threadIdx.x;   // [2][512][16]
  const int t = id >> 13, k = (id >> 4) & 511, c = id & 15;
  const float* W = t ? Wu : Wm;
  float s = 0.f;
#pragma unroll
  for (int i = 0; i < 16; ++i) s += W[k * 257 + i * 16 + c];
  ((float*)(ws + WS_CS))[id] = s;
}

// ---------------------------------------------------------------------------
extern "C" __global__ __launch_bounds__(64) void deepfm_prep2(
    const float* __restrict__ Wm, const float* __restrict__ bm,
    const float* __restrict__ Wu, const float* __restrict__ bu,
    const float* __restrict__ W1, const float* __restrict__ W2,
    const float* __restrict__ b3, char* __restrict__ ws) {
  const int bid = blockIdx.x;
  const int l = threadIdx.x;
  const int fi = l & 15, q = l >> 4;
  unsigned short h[8];
  if (bid < 576) {                       // towers: 2 x 16 kg x 18 ft
    const int t = bid / 288, rem = bid % 288;
    const int kg = rem / 18, ft = rem % 18;
    const float* W = t ? Wu : Wm;
    const float* CS = (const float*)(ws + WS_CS);
    char* outp = ws + (t ? WS_WUF : WS_WMF);
    const int f = ft * 16 + fi;
#pragma unroll
    for (int e = 0; e < 8; ++e) {
      const int k = kg * 32 + q * 8 + e;
      float val;
      if (f < 256) val = W[k * 257 + f];
      else if (f < 272) val = CS[(t * 512 + k) * 16 + (f - 256)];
      else if (f == 272) val = W[k * 257 + 256];
      else val = 0.f;
      h[e] = f2bf(val);
    }
    uint4 o;
    o.x = h[0] | ((unsigned)h[1] << 16); o.y = h[2] | ((unsigned)h[3] << 16);
    o.z = h[4] | ((unsigned)h[5] << 16); o.w = h[6] | ((unsigned)h[7] << 16);
    *(uint4*)(outp + (((kg * 18 + ft) * 64 + l) << 4)) = o;
  } else if (bid < 832) {                // W1: 16 kg x 16 ft
    const int bb = bid - 576;
    const int kg = bb / 16, ft = bb % 16;
    const int f = ft * 16 + fi;
#pragma unroll
    for (int e = 0; e < 8; ++e) h[e] = f2bf(W1[(kg * 32 + q * 8 + e) * 256 + f]);
    uint4 o;
    o.x = h[0] | ((unsigned)h[1] << 16); o.y = h[2] | ((unsigned)h[3] << 16);
    o.z = h[4] | ((unsigned)h[5] << 16); o.w = h[6] | ((unsigned)h[7] << 16);
    *(uint4*)(ws + WS_W1F + (((kg * 16 + ft) * 64 + l) << 4)) = o;
  } else if (bid < 896) {                // W2: 8 kg x 8 ft
    const int bb = bid - 832;
    const int kg = bb / 8, ft = bb % 8;
    const int f = ft * 16 + fi;
#pragma unroll
    for (int e = 0; e < 8; ++e) h[e] = f2bf(W2[(kg * 32 + q * 8 + e) * 128 + f]);
    uint4 o;
    o.x = h[0] | ((unsigned)h[1] << 16); o.y = h[2] | ((unsigned)h[3] << 16);
    o.z = h[4] | ((unsigned)h[5] << 16); o.w = h[6] | ((unsigned)h[7] << 16);
    *(uint4*)(ws + WS_W2F + (((kg * 8 + ft) * 64 + l) << 4)) = o;
  } else {                               // bias aux
    float* aux = (float*)(ws + WS_BIAS);
    if (l < 16) {
      float s = 0.f;
      for (int i = 0; i < 16; ++i) s += bm[i * 16 + l];
      aux[l] = s;
    } else if (l < 32) {
      const int k = l - 16;
      float s = 0.f;
      for (int i = 0; i < 16; ++i) s += bu[i * 16 + k];
      aux[l] = s;
    } else if (l == 32) {
      aux[32] = bm[256] + bu[256] + b3[0];
    }
  }
}

// ---------------------------------------------------------------------------
// Main fused kernel. 32 rows/block, 8 waves. Wave w: tower ft tiles {w, w+8}
// (+aux ft16 on waves 0,1 / ft17 on waves 4,5), rt in {0,1}.
// LDS: densefrag [16kg][2rt][64][16] 32KB | h1frag [8kg][2rt][64][16] 16KB
//      | outpart[32].  Total 48.5 KB -> 2 blocks/CU.
// ---------------------------------------------------------------------------
extern "C" __global__ __launch_bounds__(NTH, 4) void deepfm_main(
    const float* __restrict__ movie, const float* __restrict__ user,
    const float* __restrict__ bm, const float* __restrict__ bu,
    const float* __restrict__ b1, const float* __restrict__ b2,
    const float* __restrict__ W3, const char* __restrict__ ws,
    float* __restrict__ out) {
  __shared__ __align__(16) char densefrag[32768];
  __shared__ __align__(16) char h1frag[16384];
  __shared__ float outpart[32];

  const int tid = threadIdx.x;
  const int w   = tid >> 6;
  const int l   = tid & 63;
  const int cn  = l & 15;
  const int q   = l >> 4;
  const int row0 = blockIdx.x * RB;

  const bool doAux = (w < 2) || (w == 4) || (w == 5);
  const int  axrt  = (w < 2) ? w : (w - 4);     // rt tile for aux MFMA
  const int  axi   = (w >= 4) ? 1 : 0;          // ft16 (ms/us) vs ft17 (additive)

  if (tid < 32) outpart[tid] = 0.f;

  const f32x4 zz = {0.f, 0.f, 0.f, 0.f};
  f32x4 accA[2][2];
  f32x4 accM = zz, accU = zz;
  const float* auxb = (const float*)(ws + WS_BIAS);

  // ---------------- Phase 1: towers
  for (int t = 0; t < 2; ++t) {
    const float* inp = t ? user : movie;
    const char* WF = ws + (t ? WS_WUF : WS_WMF);
    accA[0][0] = zz; accA[0][1] = zz; accA[1][0] = zz; accA[1][1] = zz;

    const float* rbase = inp + (size_t)(row0 + cn) * 512 + q * 8;

#pragma unroll 2
    for (int kg = 0; kg < 16; ++kg) {
      const float* rp = rbase + kg * 32;
      const float4 b00 = *(const float4*)(rp);
      const float4 b01 = *(const float4*)(rp + 4);
      const float4 b10 = *(const float4*)(rp + 16 * 512);
      const float4 b11 = *(const float4*)(rp + 16 * 512 + 4);
      const bf16x8 a0 = *(const bf16x8*)(WF + (((kg * 18 + w) * 64 + l) << 4));
      const bf16x8 a1 = *(const bf16x8*)(WF + (((kg * 18 + w + 8) * 64 + l) << 4));
      const bf16x8 bf0 = cvt8(b00, b01);
      const bf16x8 bf1 = cvt8(b10, b11);
      accA[0][0] = mfma_bf16(a0, bf0, accA[0][0]);
      accA[0][1] = mfma_bf16(a0, bf1, accA[0][1]);
      accA[1][0] = mfma_bf16(a1, bf0, accA[1][0]);
      accA[1][1] = mfma_bf16(a1, bf1, accA[1][1]);
      if (doAux) {
        const bf16x8 ax = *(const bf16x8*)(WF + (((kg * 18 + 16 + axi) * 64 + l) << 4));
        const bf16x8 bsel = axrt ? bf1 : bf0;
        if (w < 2) {
          if (t == 0) accM = mfma_bf16(ax, bsel, accM);
          else        accU = mfma_bf16(ax, bsel, accU);
        } else {
          accM = mfma_bf16(ax, bsel, accM);   // additive: both towers
        }
      }
    }
    // writeback dense feats (+tower bias, no relu) into densefrag
    const float* bt = t ? bu : bm;
#pragma unroll
    for (int s = 0; s < 2; ++s) {
      const int ft = w + s * 8;
      const int fb = ft * 16 + q * 4;
      const float g0 = bt[fb], g1 = bt[fb + 1], g2 = bt[fb + 2], g3 = bt[fb + 3];
      const int kd = t * 256 + fb;
      const int kgd = kd >> 5, qd = (kd >> 3) & 3, ed = kd & 4;
#pragma unroll
      for (int rt = 0; rt < 2; ++rt) {
        const f32x4 v = accA[s][rt];
        uint2 p;
        p.x = f2bf(v[0] + g0) | ((unsigned)f2bf(v[1] + g1) << 16);
        p.y = f2bf(v[2] + g2) | ((unsigned)f2bf(v[3] + g3) << 16);
        *(uint2*)(densefrag + (((kgd * 2 + rt) * 64 + qd * 16 + cn) << 4) +
                  (ed ? 8 : 0)) = p;
      }
    }
  }

  __syncthreads();   // densefrag complete; outpart init visible

  // ---------------- FM: sum(interactions) = <ms,us>; additive term
  if (w < 2) {
    float p = 0.f;
#pragma unroll
    for (int reg = 0; reg < 4; ++reg) {
      const float msv = accM[reg] + auxb[q * 4 + reg];
      const float usv = accU[reg] + auxb[16 + q * 4 + reg];
      p += msv * usv;
    }
    p += __shfl_xor(p, 16, 64);
    p += __shfl_xor(p, 32, 64);
    if (l < 16) atomicAdd(&outpart[w * 16 + cn], p);
  } else if ((w == 4 || w == 5) && q == 0) {
    atomicAdd(&outpart[(w - 4) * 16 + cn], accM[0] + auxb[32]);
  }

  // ---------------- Phase 2: h1 = relu(all_dense @ W1 + b1)
  accA[0][0] = zz; accA[0][1] = zz; accA[1][0] = zz; accA[1][1] = zz;
  {
    const char* W1F = ws + WS_W1F;
#pragma unroll 4
    for (int kg = 0; kg < 16; ++kg) {
      const bf16x8 b0  = *(const bf16x8*)(densefrag + (((kg * 2 + 0) * 64 + l) << 4));
      const bf16x8 b1f = *(const bf16x8*)(densefrag + (((kg * 2 + 1) * 64 + l) << 4));
      const bf16x8 a0 = *(const bf16x8*)(W1F + (((kg * 16 + w) * 64 + l) << 4));
      const bf16x8 a1 = *(const bf16x8*)(W1F + (((kg * 16 + w + 8) * 64 + l) << 4));
      accA[0][0] = mfma_bf16(a0, b0,  accA[0][0]);
      accA[0][1] = mfma_bf16(a0, b1f, accA[0][1]);
      accA[1][0] = mfma_bf16(a1, b0,  accA[1][0]);
      accA[1][1] = mfma_bf16(a1, b1f, accA[1][1]);
    }
#pragma unroll
    for (int s = 0; s < 2; ++s) {
      const int ft = w + s * 8;
      const int fb = ft * 16 + q * 4;
      const float g0 = b1[fb], g1 = b1[fb + 1], g2 = b1[fb + 2], g3 = b1[fb + 3];
      const int kgd = fb >> 5, qd = (fb >> 3) & 3, ed = fb & 4;
#pragma unroll
      for (int rt = 0; rt < 2; ++rt) {
        const f32x4 v = accA[s][rt];
        uint2 p;
        p.x = f2bf(fmaxf(v[0] + g0, 0.f)) | ((unsigned)f2bf(fmaxf(v[1] + g1, 0.f)) << 16);
        p.y = f2bf(fmaxf(v[2] + g2, 0.f)) | ((unsigned)f2bf(fmaxf(v[3] + g3, 0.f)) << 16);
        *(uint2*)(h1frag + (((kgd * 2 + rt) * 64 + qd * 16 + cn) << 4) +
                  (ed ? 8 : 0)) = p;
      }
    }
  }

  __syncthreads();   // h1frag complete

  // ---------------- Phase 3: h2 = relu(h1 @ W2 + b2); out = h2 @ W3 (+FM)
  {
    f32x4 acc3[2] = {zz, zz};
    const char* W2F = ws + WS_W2F;
#pragma unroll 4
    for (int kg = 0; kg < 8; ++kg) {
      const bf16x8 b0  = *(const bf16x8*)(h1frag + (((kg * 2 + 0) * 64 + l) << 4));
      const bf16x8 b1f = *(const bf16x8*)(h1frag + (((kg * 2 + 1) * 64 + l) << 4));
      const bf16x8 a0 = *(const bf16x8*)(W2F + (((kg * 8 + w) * 64 + l) << 4));
      acc3[0] = mfma_bf16(a0, b0,  acc3[0]);
      acc3[1] = mfma_bf16(a0, b1f, acc3[1]);
    }
    const int fb = w * 16 + q * 4;       // h2 feature strip (0..127)
    float bb[4], ww[4];
#pragma unroll
    for (int i = 0; i < 4; ++i) { bb[i] = b2[fb + i]; ww[i] = W3[fb + i]; }
#pragma unroll
    for (int rt = 0; rt < 2; ++rt) {
      float p = 0.f;
#pragma unroll
      for (int reg = 0; reg < 4; ++reg)
        p += fmaxf(acc3[rt][reg] + bb[reg], 0.f) * ww[reg];
      p += __shfl_xor(p, 16, 64);
      p += __shfl_xor(p, 32, 64);
      if (l < 16) atomicAdd(&outpart[rt * 16 + cn], p);
    }
  }

  __syncthreads();
  if (tid < 32) out[row0 + tid] = outpart[tid];
}

// ---------------------------------------------------------------------------
extern "C" void kernel_launch(void* const* d_in, const int* in_sizes, int n_in,
                              void* d_out, int out_size, void* d_ws, size_t ws_size,
                              hipStream_t stream) {
  const float* movie = (const float*)d_in[0];
  const float* user  = (const float*)d_in[1];
  const float* Wm = (const float*)d_in[2];
  const float* bm = (const float*)d_in[3];
  const float* Wu = (const float*)d_in[4];
  const float* bu = (const float*)d_in[5];
  const float* W1 = (const float*)d_in[6];
  const float* b1 = (const float*)d_in[7];
  const float* W2 = (const float*)d_in[8];
  const float* b2 = (const float*)d_in[9];
  const float* W3 = (const float*)d_in[10];
  const float* b3 = (const float*)d_in[11];
  char* ws = (char*)d_ws;
  float* out = (float*)d_out;

  deepfm_prep1<<<64, 256, 0, stream>>>(Wm, Wu, ws);
  deepfm_prep2<<<897, 64, 0, stream>>>(Wm, bm, Wu, bu, W1, W2, b3, ws);
  deepfm_main<<<512, NTH, 0, stream>>>(movie, user, bm, bu, b1, b2, W3, ws, out);
}